// Round 4
// baseline (80.026 us; speedup 1.0000x reference)
//
#include <hip/hip_runtime.h>
#include <hip/hip_bf16.h>

#define B_ 32
#define D_ 512
#define N_ 1024
#define M_ 1024
#define BM 128
#define BK 64
#define NSTEP (D_ / BK)   // 8

typedef __attribute__((ext_vector_type(8))) short bf16x8;
typedef __attribute__((ext_vector_type(4))) float f32x4;
typedef __attribute__((ext_vector_type(4))) int   i32x4;
typedef unsigned short ushort_t;

__device__ __forceinline__ unsigned map_f(float f) {
    unsigned b = __float_as_uint(f);
    return (b & 0x80000000u) ? ~b : (b | 0x80000000u);
}

// ============================================================================
// Pass 1: convert fp32 [b][d=512][j=1024] -> bf16 [b][j=1024][d=512]
// Pure register 4x4 transpose, no LDS, fully-coalesced 8B stores (128B/16 lanes).
// 8192 blocks x 256 threads; each block does one 64x64 tile of one array.
// ============================================================================
__global__ __launch_bounds__(256)
void cvt_transpose_kernel(const float* __restrict__ e1, const float* __restrict__ e2,
                          ushort_t* __restrict__ w1, ushort_t* __restrict__ w2) {
    const int id  = blockIdx.x;
    const int arr = id >> 12;           // 4096 tiles per array
    const int rem = id & 4095;
    const int b   = rem >> 7;           // 128 tiles per batch (16 jt x 8 kt)
    const int jt  = (rem & 127) >> 3;
    const int kt  = rem & 7;
    const float* src = (arr ? e2 : e1) + (size_t)b * D_ * N_ + (size_t)(kt * 64) * N_ + jt * 64;
    ushort_t*    dst = (arr ? w2 : w1) + (size_t)b * N_ * D_ + (size_t)(jt * 64) * D_ + kt * 64;

    const int t  = threadIdx.x;
    const int kq = t & 15;    // k-subblock: rows k = 4*kq .. 4*kq+3
    const int jq = t >> 4;    // j-subblock: cols j = 4*jq .. 4*jq+3

    float4 fl[4];
    #pragma unroll
    for (int kl = 0; kl < 4; ++kl)
        fl[kl] = *reinterpret_cast<const float4*>(src + (size_t)(kq * 4 + kl) * N_ + jq * 4);

    #pragma unroll
    for (int jl = 0; jl < 4; ++jl) {
        __hip_bfloat162 h0 = __float22bfloat162_rn(
            make_float2(reinterpret_cast<const float*>(&fl[0])[jl],
                        reinterpret_cast<const float*>(&fl[1])[jl]));
        __hip_bfloat162 h1 = __float22bfloat162_rn(
            make_float2(reinterpret_cast<const float*>(&fl[2])[jl],
                        reinterpret_cast<const float*>(&fl[3])[jl]));
        uint2 v = make_uint2(*reinterpret_cast<unsigned*>(&h0),
                             *reinterpret_cast<unsigned*>(&h1));
        // 8B store; lanes kq=0..15 contiguous -> 128B coalesced per j-row
        *reinterpret_cast<uint2*>(dst + (size_t)(jq * 4 + jl) * D_ + kq * 4) = v;
    }
}

// ============================================================================
// Pass 2: bf16 GEMM-max, m97-style 2-phase with global_load_lds staging.
// LDS layout per tile: byte = j*128 + 16*(q ^ (j&7)), q = k-granule (8 bf16).
// Staging writes LINEAR LDS; the swizzle is applied to the GLOBAL source addr.
// ============================================================================
struct __align__(16) GSmem {
    ushort_t As[2][BM * BK];
    ushort_t Bs[2][BM * BK];
    float red[4];
};

__device__ __forceinline__ void stage_lds(const ushort_t* __restrict__ wsrc,
                                          ushort_t* lds_tile, int k0, int wave, int lane) {
    #pragma unroll
    for (int i = 0; i < 4; ++i) {
        const int jb = wave * 32 + i * 8;
        const int j  = jb + (lane >> 3);
        const int q  = (lane & 7) ^ (j & 7);           // inverse-swizzled source granule
        const char* gp = (const char*)wsrc + (size_t)j * (D_ * 2) + k0 * 2 + q * 16;
        char* lp = (char*)lds_tile + (wave * 4 + i) * 1024;   // wave-uniform base
        __builtin_amdgcn_global_load_lds(
            (const __attribute__((address_space(1))) unsigned int*)gp,
            (__attribute__((address_space(3))) unsigned int*)lp, 16, 0, 0);
    }
}

__global__ __launch_bounds__(256, 2)
void gemm_bf16_kernel(const ushort_t* __restrict__ w1, const ushort_t* __restrict__ w2,
                      float* __restrict__ out) {
    __shared__ GSmem sm;
    const int wg  = blockIdx.x;
    const int swz = (wg & 7) * 256 + (wg >> 3);   // XCD swizzle (2048 % 8 == 0)
    const int b    = swz >> 6;
    const int tile = swz & 63;
    const int tn = (tile >> 3) * BM;
    const int tc = (tile & 7) * BM;

    const int t    = threadIdx.x;
    const int lane = t & 63;
    const int wave = t >> 6;
    const int l15  = lane & 15;
    const int l4   = lane >> 4;
    const int wr   = (wave >> 1) * 64;
    const int wc   = (wave & 1) * 64;

    const ushort_t* Aw = w1 + (size_t)b * N_ * D_ + (size_t)tn * D_;
    const ushort_t* Bw = w2 + (size_t)b * M_ * D_ + (size_t)tc * D_;

    f32x4 acc[4][4] = {};

    stage_lds(Aw, sm.As[0], 0, wave, lane);
    stage_lds(Bw, sm.Bs[0], 0, wave, lane);
    asm volatile("s_waitcnt vmcnt(0)" ::: "memory");
    __syncthreads();

    int cur = 0;
    #pragma unroll 1
    for (int ks = 0; ks < NSTEP; ++ks) {
        if (ks < NSTEP - 1) {   // async prefetch of next K-tile while computing this one
            stage_lds(Aw, sm.As[cur ^ 1], (ks + 1) * BK, wave, lane);
            stage_lds(Bw, sm.Bs[cur ^ 1], (ks + 1) * BK, wave, lane);
        }
        const char* Ab = (const char*)sm.As[cur];
        const char* Bb = (const char*)sm.Bs[cur];
        #pragma unroll
        for (int kk = 0; kk < 2; ++kk) {
            bf16x8 afrag[4], bfrag[4];
            const int q = 4 * kk + l4;
            #pragma unroll
            for (int m = 0; m < 4; ++m) {
                const int j = wr + m * 16 + l15;
                afrag[m] = *reinterpret_cast<const bf16x8*>(Ab + j * 128 + 16 * (q ^ (j & 7)));
            }
            #pragma unroll
            for (int n = 0; n < 4; ++n) {
                const int j = wc + n * 16 + l15;
                bfrag[n] = *reinterpret_cast<const bf16x8*>(Bb + j * 128 + 16 * (q ^ (j & 7)));
            }
            #pragma unroll
            for (int m = 0; m < 4; ++m)
                #pragma unroll
                for (int n = 0; n < 4; ++n)
                    acc[m][n] = __builtin_amdgcn_mfma_f32_16x16x32_bf16(
                        afrag[m], bfrag[n], acc[m][n], 0, 0, 0);
        }
        asm volatile("s_waitcnt vmcnt(0)" ::: "memory");   // prefetched tile landed
        __syncthreads();
        cur ^= 1;
    }

    float tmax = acc[0][0][0];
    #pragma unroll
    for (int m = 0; m < 4; ++m)
        #pragma unroll
        for (int n = 0; n < 4; ++n)
            #pragma unroll
            for (int i = 0; i < 4; ++i)
                tmax = fmaxf(tmax, acc[m][n][i]);
    #pragma unroll
    for (int off = 32; off; off >>= 1)
        tmax = fmaxf(tmax, __shfl_xor(tmax, off));
    if (lane == 0) sm.red[wave] = tmax;
    __syncthreads();
    if (t == 0) {
        float m4 = fmaxf(fmaxf(sm.red[0], sm.red[1]), fmaxf(sm.red[2], sm.red[3]));
        atomicMax(reinterpret_cast<unsigned*>(out) + b, map_f(m4));
    }
}

// ============================================================================
// Fallback (ws too small): round-2 fused fp32->bf16 staging kernel.
// ============================================================================
struct __align__(16) FSmem {
    ushort_t As[2][BM * BK];
    ushort_t Bs[2][BM * BK];
    float red[4];
};

__device__ __forceinline__ void load8(const float* __restrict__ src, int t, float4* fl) {
    const int q  = t & 7;
    const int jg = t >> 3;
    const float* p = src + (size_t)(q * 8) * N_ + jg * 4;
    #pragma unroll
    for (int dd = 0; dd < 8; ++dd)
        fl[dd] = *reinterpret_cast<const float4*>(p + (size_t)dd * N_);
}

__device__ __forceinline__ void flush8(const float4* fl, char* lds, int t) {
    const int q  = t & 7;
    const int jg = t >> 3;
    #pragma unroll
    for (int i = 0; i < 4; ++i) {
        const int j = jg * 4 + i;
        unsigned w[4];
        #pragma unroll
        for (int wi = 0; wi < 4; ++wi) {
            float2 f2 = make_float2(reinterpret_cast<const float*>(&fl[2 * wi])[i],
                                    reinterpret_cast<const float*>(&fl[2 * wi + 1])[i]);
            __hip_bfloat162 h2 = __float22bfloat162_rn(f2);
            w[wi] = *reinterpret_cast<unsigned*>(&h2);
        }
        i32x4 vv = { (int)w[0], (int)w[1], (int)w[2], (int)w[3] };
        *reinterpret_cast<i32x4*>(lds + j * 128 + 16 * (q ^ (j & 7))) = vv;
    }
}

__global__ __launch_bounds__(256, 2)
void gemm_max_kernel(const float* __restrict__ e1, const float* __restrict__ e2,
                     float* __restrict__ out) {
    __shared__ FSmem sm;
    const int wg  = blockIdx.x;
    const int swz = (wg & 7) * 256 + (wg >> 3);
    const int b    = swz >> 6;
    const int tile = swz & 63;
    const int tn = (tile >> 3) * BM;
    const int tc = (tile & 7) * BM;
    const int t    = threadIdx.x;
    const int lane = t & 63;
    const int wave = t >> 6;
    const int l15  = lane & 15;
    const int l4   = lane >> 4;
    const int wr   = (wave >> 1) * 64;
    const int wc   = (wave & 1) * 64;
    const float* e1b = e1 + (size_t)b * D_ * N_ + tn;
    const float* e2b = e2 + (size_t)b * D_ * M_ + tc;
    f32x4 acc[4][4] = {};
    float4 flA[8], flB[8];
    load8(e1b, t, flA);
    load8(e2b, t, flB);
    flush8(flA, (char*)sm.As[0], t);
    flush8(flB, (char*)sm.Bs[0], t);
    load8(e1b + (size_t)BK * N_, t, flA);
    load8(e2b + (size_t)BK * M_, t, flB);
    int cur = 0;
    #pragma unroll 1
    for (int ks = 0; ks < NSTEP; ++ks) {
        __syncthreads();
        const char* Ab = (const char*)sm.As[cur];
        const char* Bb = (const char*)sm.Bs[cur];
        #pragma unroll
        for (int kk = 0; kk < 2; ++kk) {
            bf16x8 afrag[4], bfrag[4];
            const int q = 4 * kk + l4;
            #pragma unroll
            for (int m = 0; m < 4; ++m) {
                const int j = wr + m * 16 + l15;
                afrag[m] = *reinterpret_cast<const bf16x8*>(Ab + j * 128 + 16 * (q ^ (j & 7)));
            }
            #pragma unroll
            for (int n = 0; n < 4; ++n) {
                const int j = wc + n * 16 + l15;
                bfrag[n] = *reinterpret_cast<const bf16x8*>(Bb + j * 128 + 16 * (q ^ (j & 7)));
            }
            #pragma unroll
            for (int m = 0; m < 4; ++m)
                #pragma unroll
                for (int n = 0; n < 4; ++n)
                    acc[m][n] = __builtin_amdgcn_mfma_f32_16x16x32_bf16(
                        afrag[m], bfrag[n], acc[m][n], 0, 0, 0);
        }
        if (ks < NSTEP - 1) {
            flush8(flA, (char*)sm.As[cur ^ 1], t);
            flush8(flB, (char*)sm.Bs[cur ^ 1], t);
            if (ks < NSTEP - 2) {
                load8(e1b + (size_t)(ks + 2) * BK * N_, t, flA);
                load8(e2b + (size_t)(ks + 2) * BK * M_, t, flB);
            }
        }
        cur ^= 1;
    }
    float tmax = acc[0][0][0];
    #pragma unroll
    for (int m = 0; m < 4; ++m)
        #pragma unroll
        for (int n = 0; n < 4; ++n)
            #pragma unroll
            for (int i = 0; i < 4; ++i)
                tmax = fmaxf(tmax, acc[m][n][i]);
    #pragma unroll
    for (int off = 32; off; off >>= 1)
        tmax = fmaxf(tmax, __shfl_xor(tmax, off));
    if (lane == 0) sm.red[wave] = tmax;
    __syncthreads();
    if (t == 0) {
        float m4 = fmaxf(fmaxf(sm.red[0], sm.red[1]), fmaxf(sm.red[2], sm.red[3]));
        atomicMax(reinterpret_cast<unsigned*>(out) + b, map_f(m4));
    }
}

__global__ void finalize_kernel(float* out) {
    const int i = threadIdx.x;
    unsigned u = reinterpret_cast<unsigned*>(out)[i];
    out[i] = __uint_as_float((u & 0x80000000u) ? (u ^ 0x80000000u) : ~u);
}

extern "C" void kernel_launch(void* const* d_in, const int* in_sizes, int n_in,
                              void* d_out, int out_size, void* d_ws, size_t ws_size,
                              hipStream_t stream) {
    const float* e1 = (const float*)d_in[0];
    const float* e2 = (const float*)d_in[1];
    float* out = (float*)d_out;

    hipMemsetAsync(d_out, 0, B_ * sizeof(float), stream);  // 0 == -inf under map_f

    const size_t need = (size_t)2 * B_ * N_ * D_ * sizeof(ushort_t);  // 64 MB
    if (ws_size >= need) {
        ushort_t* w1 = (ushort_t*)d_ws;
        ushort_t* w2 = w1 + (size_t)B_ * N_ * D_;
        cvt_transpose_kernel<<<8192, 256, 0, stream>>>(e1, e2, w1, w2);
        gemm_bf16_kernel<<<2048, 256, 0, stream>>>(w1, w2, out);
    } else {
        gemm_max_kernel<<<2048, 256, 0, stream>>>(e1, e2, out);
    }
    finalize_kernel<<<1, B_, 0, stream>>>(out);
}

// Round 5
// 77.747 us; speedup vs baseline: 1.0293x; 1.0293x over previous
//
#include <hip/hip_runtime.h>
#include <hip/hip_bf16.h>

#define B_ 32
#define D_ 512
#define N_ 1024
#define M_ 1024
#define BM 128
#define BK 64
#define NSTEP (D_ / BK)   // 8

typedef __attribute__((ext_vector_type(8))) short bf16x8;
typedef __attribute__((ext_vector_type(4))) short s16x4;
typedef __attribute__((ext_vector_type(4))) float f32x4;
typedef __attribute__((ext_vector_type(4))) int   i32x4;
typedef unsigned short ushort_t;

__device__ __forceinline__ unsigned map_f(float f) {
    unsigned b = __float_as_uint(f);
    return (b & 0x80000000u) ? ~b : (b | 0x80000000u);
}

// ============================================================================
// Pass 1: pure streaming cvt fp32 [b][d][n] -> bf16 [b][d][n]. NO transpose:
// fully coalesced 32B reads / 16B writes per lane. grid = (8192, 2).
// ============================================================================
__global__ __launch_bounds__(256)
void cvt_stream_kernel(const float* __restrict__ e1, const float* __restrict__ e2,
                       ushort_t* __restrict__ w1, ushort_t* __restrict__ w2) {
    const float* src = blockIdx.y ? e2 : e1;
    ushort_t*    dst = blockIdx.y ? w2 : w1;
    const size_t i = ((size_t)blockIdx.x * 256 + threadIdx.x) * 8;
    float4 a = *reinterpret_cast<const float4*>(src + i);
    float4 b = *reinterpret_cast<const float4*>(src + i + 4);
    __hip_bfloat162 h0 = __float22bfloat162_rn(make_float2(a.x, a.y));
    __hip_bfloat162 h1 = __float22bfloat162_rn(make_float2(a.z, a.w));
    __hip_bfloat162 h2 = __float22bfloat162_rn(make_float2(b.x, b.y));
    __hip_bfloat162 h3 = __float22bfloat162_rn(make_float2(b.z, b.w));
    i32x4 v = { *reinterpret_cast<int*>(&h0), *reinterpret_cast<int*>(&h1),
                *reinterpret_cast<int*>(&h2), *reinterpret_cast<int*>(&h3) };
    *reinterpret_cast<i32x4*>(dst + i) = v;
}

// ============================================================================
// Pass 2: bf16 GEMM-max from [b][d][n] bf16 workspace.
// LDS tile [k=64][j=128] bf16 (256B rows), 16B-granule swizzle Q' = Q ^ 2*(k&3).
// Staged via global_load_lds (linear dest + inverse-swizzled global source).
// Fragments gathered with ds_read_b64_tr_b16 (HW transpose read).
// ============================================================================
struct __align__(16) GSmem {
    ushort_t As[2][BM * BK];   // As[0]@0, As[1]@16384, Bs[0]@32768, Bs[1]@49152
    ushort_t Bs[2][BM * BK];
    float red[4];
};

// Stage one [64][128] bf16 tile (global row stride 2048B) into LDS linearly;
// source granule pre-swizzled so that LDS (k, Q') holds global granule Q'^(2*(k&3)).
__device__ __forceinline__ void stage_lds(const ushort_t* __restrict__ gpanel, int k0,
                                          ushort_t* lds_tile, int wave, int lane) {
    #pragma unroll
    for (int i = 0; i < 4; ++i) {
        const int reg = wave * 4 + i;            // 16 regions of 4 k-rows
        const int k   = k0 + reg * 4 + (lane >> 4);
        const int Q   = (lane & 15) ^ (2 * (k & 3));
        const char* gp = (const char*)gpanel + (size_t)k * (N_ * 2) + Q * 16;
        char* lp = (char*)lds_tile + reg * 1024;  // wave-uniform base (+lane*16 implicit)
        __builtin_amdgcn_global_load_lds(
            (const __attribute__((address_space(1))) unsigned int*)gp,
            (__attribute__((address_space(3))) unsigned int*)lp, 16, 0, 0);
    }
}

__global__ __launch_bounds__(256, 2)
void gemm_bf16_kernel(const ushort_t* __restrict__ w1, const ushort_t* __restrict__ w2,
                      float* __restrict__ out) {
    __shared__ GSmem sm;
    const int wg  = blockIdx.x;
    const int swz = (wg & 7) * 256 + (wg >> 3);   // XCD swizzle (2048 % 8 == 0)
    const int b    = swz >> 6;
    const int tile = swz & 63;
    const int tn = (tile >> 3) * BM;
    const int tc = (tile & 7) * BM;

    const int t    = threadIdx.x;
    const int lane = t & 63;
    const int wave = t >> 6;
    const int wr   = (wave >> 1) * 64;   // A j-quadrant
    const int wc   = (wave & 1) * 64;    // B j-quadrant

    // tr_read per-lane geometry
    const int c = lane & 15, g = lane >> 4;
    const int r = c >> 2, d = (c >> 1) & 1, h = c & 1;

    const unsigned ldsA0 = (unsigned)(uintptr_t)&sm.As[0][0];
    unsigned tbA[4], tbB[4];
    #pragma unroll
    for (int m = 0; m < 4; ++m)
        tbA[m] = ldsA0 + (8 * g + r) * 256
               + 16 * ((((wr >> 3) + 2 * m + d) ^ (2 * r))) + 8 * h;
    #pragma unroll
    for (int n = 0; n < 4; ++n)
        tbB[n] = ldsA0 + 32768 + (8 * g + r) * 256
               + 16 * ((((wc >> 3) + 2 * n + d) ^ (2 * r))) + 8 * h;

    const ushort_t* Ap = w1 + (size_t)b * D_ * N_ + tn;
    const ushort_t* Bp = w2 + (size_t)b * D_ * M_ + tc;

    f32x4 acc[4][4] = {};

    stage_lds(Ap, 0, sm.As[0], wave, lane);
    stage_lds(Bp, 0, sm.Bs[0], wave, lane);
    asm volatile("s_waitcnt vmcnt(0)" ::: "memory");
    __syncthreads();

    int cur = 0;
    #pragma unroll 1
    for (int ks = 0; ks < NSTEP; ++ks) {
        if (ks < NSTEP - 1) {   // async prefetch of next K-tile into the other buffer
            stage_lds(Ap, (ks + 1) * BK, sm.As[cur ^ 1], wave, lane);
            stage_lds(Bp, (ks + 1) * BK, sm.Bs[cur ^ 1], wave, lane);
        }
        const unsigned off = (unsigned)cur * 16384u;
        #pragma unroll
        for (int kk = 0; kk < 2; ++kk) {
            s16x4 alo[4], ahi[4], blo[4], bhi[4];
            #pragma unroll
            for (int m = 0; m < 4; ++m) {
                asm volatile("ds_read_b64_tr_b16 %0, %1 offset:%2"
                             : "=v"(alo[m]) : "v"(tbA[m] + off), "n"(kk * 8192));
                asm volatile("ds_read_b64_tr_b16 %0, %1 offset:%2"
                             : "=v"(ahi[m]) : "v"(tbA[m] + off), "n"(kk * 8192 + 1024));
            }
            #pragma unroll
            for (int n = 0; n < 4; ++n) {
                asm volatile("ds_read_b64_tr_b16 %0, %1 offset:%2"
                             : "=v"(blo[n]) : "v"(tbB[n] + off), "n"(kk * 8192));
                asm volatile("ds_read_b64_tr_b16 %0, %1 offset:%2"
                             : "=v"(bhi[n]) : "v"(tbB[n] + off), "n"(kk * 8192 + 1024));
            }
            asm volatile("s_waitcnt lgkmcnt(0)" ::: "memory");
            __builtin_amdgcn_sched_barrier(0);
            bf16x8 af[4], bf[4];
            #pragma unroll
            for (int m = 0; m < 4; ++m)
                af[m] = __builtin_shufflevector(alo[m], ahi[m], 0, 1, 2, 3, 4, 5, 6, 7);
            #pragma unroll
            for (int n = 0; n < 4; ++n)
                bf[n] = __builtin_shufflevector(blo[n], bhi[n], 0, 1, 2, 3, 4, 5, 6, 7);
            #pragma unroll
            for (int m = 0; m < 4; ++m)
                #pragma unroll
                for (int n = 0; n < 4; ++n)
                    acc[m][n] = __builtin_amdgcn_mfma_f32_16x16x32_bf16(
                        af[m], bf[n], acc[m][n], 0, 0, 0);
        }
        asm volatile("s_waitcnt vmcnt(0)" ::: "memory");   // prefetched tile landed
        __syncthreads();
        cur ^= 1;
    }

    float tmax = acc[0][0][0];
    #pragma unroll
    for (int m = 0; m < 4; ++m)
        #pragma unroll
        for (int n = 0; n < 4; ++n)
            #pragma unroll
            for (int i = 0; i < 4; ++i)
                tmax = fmaxf(tmax, acc[m][n][i]);
    #pragma unroll
    for (int off2 = 32; off2; off2 >>= 1)
        tmax = fmaxf(tmax, __shfl_xor(tmax, off2));
    if (lane == 0) sm.red[wave] = tmax;
    __syncthreads();
    if (t == 0) {
        float m4 = fmaxf(fmaxf(sm.red[0], sm.red[1]), fmaxf(sm.red[2], sm.red[3]));
        atomicMax(reinterpret_cast<unsigned*>(out) + b, map_f(m4));
    }
}

// ============================================================================
// Fallback (ws too small): round-2 fused fp32->bf16 staging kernel.
// ============================================================================
struct __align__(16) FSmem {
    ushort_t As[2][BM * BK];
    ushort_t Bs[2][BM * BK];
    float red[4];
};

__device__ __forceinline__ void load8(const float* __restrict__ src, int t, float4* fl) {
    const int q  = t & 7;
    const int jg = t >> 3;
    const float* p = src + (size_t)(q * 8) * N_ + jg * 4;
    #pragma unroll
    for (int dd = 0; dd < 8; ++dd)
        fl[dd] = *reinterpret_cast<const float4*>(p + (size_t)dd * N_);
}

__device__ __forceinline__ void flush8(const float4* fl, char* lds, int t) {
    const int q  = t & 7;
    const int jg = t >> 3;
    #pragma unroll
    for (int i = 0; i < 4; ++i) {
        const int j = jg * 4 + i;
        unsigned w[4];
        #pragma unroll
        for (int wi = 0; wi < 4; ++wi) {
            float2 f2 = make_float2(reinterpret_cast<const float*>(&fl[2 * wi])[i],
                                    reinterpret_cast<const float*>(&fl[2 * wi + 1])[i]);
            __hip_bfloat162 h2 = __float22bfloat162_rn(f2);
            w[wi] = *reinterpret_cast<unsigned*>(&h2);
        }
        i32x4 vv = { (int)w[0], (int)w[1], (int)w[2], (int)w[3] };
        *reinterpret_cast<i32x4*>(lds + j * 128 + 16 * (q ^ (j & 7))) = vv;
    }
}

__global__ __launch_bounds__(256, 2)
void gemm_max_kernel(const float* __restrict__ e1, const float* __restrict__ e2,
                     float* __restrict__ out) {
    __shared__ FSmem sm;
    const int wg  = blockIdx.x;
    const int swz = (wg & 7) * 256 + (wg >> 3);
    const int b    = swz >> 6;
    const int tile = swz & 63;
    const int tn = (tile >> 3) * BM;
    const int tc = (tile & 7) * BM;
    const int t    = threadIdx.x;
    const int lane = t & 63;
    const int wave = t >> 6;
    const int l15  = lane & 15;
    const int l4   = lane >> 4;
    const int wr   = (wave >> 1) * 64;
    const int wc   = (wave & 1) * 64;
    const float* e1b = e1 + (size_t)b * D_ * N_ + tn;
    const float* e2b = e2 + (size_t)b * D_ * M_ + tc;
    f32x4 acc[4][4] = {};
    float4 flA[8], flB[8];
    load8(e1b, t, flA);
    load8(e2b, t, flB);
    flush8(flA, (char*)sm.As[0], t);
    flush8(flB, (char*)sm.Bs[0], t);
    load8(e1b + (size_t)BK * N_, t, flA);
    load8(e2b + (size_t)BK * M_, t, flB);
    int cur = 0;
    #pragma unroll 1
    for (int ks = 0; ks < NSTEP; ++ks) {
        __syncthreads();
        const char* Ab = (const char*)sm.As[cur];
        const char* Bb = (const char*)sm.Bs[cur];
        #pragma unroll
        for (int kk = 0; kk < 2; ++kk) {
            bf16x8 afrag[4], bfrag[4];
            const int q = 4 * kk + l4;
            #pragma unroll
            for (int m = 0; m < 4; ++m) {
                const int j = wr + m * 16 + l15;
                afrag[m] = *reinterpret_cast<const bf16x8*>(Ab + j * 128 + 16 * (q ^ (j & 7)));
            }
            #pragma unroll
            for (int n = 0; n < 4; ++n) {
                const int j = wc + n * 16 + l15;
                bfrag[n] = *reinterpret_cast<const bf16x8*>(Bb + j * 128 + 16 * (q ^ (j & 7)));
            }
            #pragma unroll
            for (int m = 0; m < 4; ++m)
                #pragma unroll
                for (int n = 0; n < 4; ++n)
                    acc[m][n] = __builtin_amdgcn_mfma_f32_16x16x32_bf16(
                        afrag[m], bfrag[n], acc[m][n], 0, 0, 0);
        }
        if (ks < NSTEP - 1) {
            flush8(flA, (char*)sm.As[cur ^ 1], t);
            flush8(flB, (char*)sm.Bs[cur ^ 1], t);
            if (ks < NSTEP - 2) {
                load8(e1b + (size_t)(ks + 2) * BK * N_, t, flA);
                load8(e2b + (size_t)(ks + 2) * BK * M_, t, flB);
            }
        }
        cur ^= 1;
    }
    float tmax = acc[0][0][0];
    #pragma unroll
    for (int m = 0; m < 4; ++m)
        #pragma unroll
        for (int n = 0; n < 4; ++n)
            #pragma unroll
            for (int i = 0; i < 4; ++i)
                tmax = fmaxf(tmax, acc[m][n][i]);
    #pragma unroll
    for (int off = 32; off; off >>= 1)
        tmax = fmaxf(tmax, __shfl_xor(tmax, off));
    if (lane == 0) sm.red[wave] = tmax;
    __syncthreads();
    if (t == 0) {
        float m4 = fmaxf(fmaxf(sm.red[0], sm.red[1]), fmaxf(sm.red[2], sm.red[3]));
        atomicMax(reinterpret_cast<unsigned*>(out) + b, map_f(m4));
    }
}

__global__ void finalize_kernel(float* out) {
    const int i = threadIdx.x;
    unsigned u = reinterpret_cast<unsigned*>(out)[i];
    out[i] = __uint_as_float((u & 0x80000000u) ? (u ^ 0x80000000u) : ~u);
}

extern "C" void kernel_launch(void* const* d_in, const int* in_sizes, int n_in,
                              void* d_out, int out_size, void* d_ws, size_t ws_size,
                              hipStream_t stream) {
    const float* e1 = (const float*)d_in[0];
    const float* e2 = (const float*)d_in[1];
    float* out = (float*)d_out;

    hipMemsetAsync(d_out, 0, B_ * sizeof(float), stream);  // 0 == -inf under map_f

    const size_t need = (size_t)2 * B_ * N_ * D_ * sizeof(ushort_t);  // 64 MB
    if (ws_size >= need) {
        ushort_t* w1 = (ushort_t*)d_ws;
        ushort_t* w2 = w1 + (size_t)B_ * N_ * D_;
        cvt_stream_kernel<<<dim3(8192, 2), 256, 0, stream>>>(e1, e2, w1, w2);
        gemm_bf16_kernel<<<2048, 256, 0, stream>>>(w1, w2, out);
    } else {
        gemm_max_kernel<<<2048, 256, 0, stream>>>(e1, e2, out);
    }
    finalize_kernel<<<1, B_, 0, stream>>>(out);
}